// Round 1
// baseline (24201.686 us; speedup 1.0000x reference)
//
#include <hip/hip_runtime.h>

// RetinaNet head: 2 heads x 5 scales x (4x conv3x3(256->256)+ReLU, conv3x3(256->A*k)).
// Conv as implicit GEMM: out[oc,p] = sum_{ic,s} w[oc, ic*9+s] * x[ic, shifted p].
// Round 1: fp32 LDS-tiled GEMM (64x64 tile, K-step 16, 4x4 per thread).

constexpr int IC   = 256;
constexpr int KTOT = IC * 9;   // 2304
constexpr int TM = 64, TN = 64, TK = 16;

// x: [N, IC, H*W]  w: [256, 2304]  bias: [256]  y: [N, 256, H*W]   (ReLU)
__global__ __launch_bounds__(256, 4)
void conv3x3_mid(const float* __restrict__ x, const float* __restrict__ w,
                 const float* __restrict__ bias, float* __restrict__ y,
                 int H, int W, int Wshift)
{
    const int M  = H * W;
    const int n  = blockIdx.z;
    const float* xb = x + (size_t)n * IC * M;
    float*       yb = y + (size_t)n * 256 * M;
    const int p0  = blockIdx.x * TM;
    const int oc0 = blockIdx.y * TN;
    const int tx = threadIdx.x;   // 0..15 -> pixels
    const int ty = threadIdx.y;   // 0..15 -> out channels
    const int tid = ty * 16 + tx;

    __shared__ float As[TK][TN + 1];   // [k][oc]
    __shared__ float Bs[TK][TM + 1];   // [k][pixel]

    float acc[4][4] = {};

    for (int k0 = 0; k0 < KTOT; k0 += TK) {
        // --- stage A (weights): 16 k x 64 oc ---
        #pragma unroll
        for (int l = 0; l < 4; l++) {
            int e  = tid + 256 * l;
            int oc = e >> 4;
            int kk = e & 15;
            As[kk][oc] = w[(size_t)(oc0 + oc) * KTOT + (k0 + kk)];
        }
        // --- stage B (shifted input): 16 k x 64 pixels ---
        #pragma unroll
        for (int l = 0; l < 4; l++) {
            int e  = tid + 256 * l;
            int kk = e >> 6;
            int pl = e & 63;
            int kg = k0 + kk;
            int ic = kg / 9;
            int s  = kg - ic * 9;
            int q3 = s / 3;
            int dy = q3 - 1;
            int dx = (s - q3 * 3) - 1;
            int p  = p0 + pl;
            int py = p >> Wshift;
            int px = p & (W - 1);
            int yy = py + dy, xx = px + dx;
            float v = 0.0f;
            if ((unsigned)yy < (unsigned)H && (unsigned)xx < (unsigned)W)
                v = xb[(size_t)ic * M + (yy << Wshift) + xx];
            Bs[kk][pl] = v;
        }
        __syncthreads();
        #pragma unroll
        for (int kk = 0; kk < TK; kk++) {
            float a[4], b[4];
            #pragma unroll
            for (int j = 0; j < 4; j++) a[j] = As[kk][ty + 16 * j];
            #pragma unroll
            for (int i = 0; i < 4; i++) b[i] = Bs[kk][tx + 16 * i];
            #pragma unroll
            for (int j = 0; j < 4; j++)
                #pragma unroll
                for (int i = 0; i < 4; i++)
                    acc[j][i] += a[j] * b[i];
        }
        __syncthreads();
    }

    #pragma unroll
    for (int j = 0; j < 4; j++) {
        int oc = oc0 + ty + 16 * j;
        float bv = bias[oc];
        #pragma unroll
        for (int i = 0; i < 4; i++) {
            int p = p0 + tx + 16 * i;
            float v = acc[j][i] + bv;
            yb[(size_t)oc * M + p] = v > 0.0f ? v : 0.0f;
        }
    }
}

// Final conv: OC = 9*kout channels, writes permuted [N, (anchor_off + p*9 + a)*kout + c]
__global__ __launch_bounds__(256, 4)
void conv3x3_final(const float* __restrict__ x, const float* __restrict__ w,
                   const float* __restrict__ bias, float* __restrict__ out,
                   int H, int W, int Wshift, int OC, int kout,
                   int anchor_off, int atot)
{
    const int M  = H * W;
    const int n  = blockIdx.z;
    const float* xb = x + (size_t)n * IC * M;
    float*       ob = out + (size_t)n * atot * kout;
    const int p0  = blockIdx.x * TM;
    const int oc0 = blockIdx.y * TN;
    const int tx = threadIdx.x;
    const int ty = threadIdx.y;
    const int tid = ty * 16 + tx;

    __shared__ float As[TK][TN + 1];
    __shared__ float Bs[TK][TM + 1];

    float acc[4][4] = {};

    for (int k0 = 0; k0 < KTOT; k0 += TK) {
        #pragma unroll
        for (int l = 0; l < 4; l++) {
            int e  = tid + 256 * l;
            int oc = e >> 4;
            int kk = e & 15;
            int ocg = oc0 + oc;
            As[kk][oc] = (ocg < OC) ? w[(size_t)ocg * KTOT + (k0 + kk)] : 0.0f;
        }
        #pragma unroll
        for (int l = 0; l < 4; l++) {
            int e  = tid + 256 * l;
            int kk = e >> 6;
            int pl = e & 63;
            int kg = k0 + kk;
            int ic = kg / 9;
            int s  = kg - ic * 9;
            int q3 = s / 3;
            int dy = q3 - 1;
            int dx = (s - q3 * 3) - 1;
            int p  = p0 + pl;
            int py = p >> Wshift;
            int px = p & (W - 1);
            int yy = py + dy, xx = px + dx;
            float v = 0.0f;
            if ((unsigned)yy < (unsigned)H && (unsigned)xx < (unsigned)W)
                v = xb[(size_t)ic * M + (yy << Wshift) + xx];
            Bs[kk][pl] = v;
        }
        __syncthreads();
        #pragma unroll
        for (int kk = 0; kk < TK; kk++) {
            float a[4], b[4];
            #pragma unroll
            for (int j = 0; j < 4; j++) a[j] = As[kk][ty + 16 * j];
            #pragma unroll
            for (int i = 0; i < 4; i++) b[i] = Bs[kk][tx + 16 * i];
            #pragma unroll
            for (int j = 0; j < 4; j++)
                #pragma unroll
                for (int i = 0; i < 4; i++)
                    acc[j][i] += a[j] * b[i];
        }
        __syncthreads();
    }

    #pragma unroll
    for (int j = 0; j < 4; j++) {
        int oc = oc0 + ty + 16 * j;
        if (oc < OC) {
            int a = oc / kout;
            int c = oc - a * kout;
            float bv = bias[oc];
            #pragma unroll
            for (int i = 0; i < 4; i++) {
                int p = p0 + tx + 16 * i;
                ob[(size_t)(anchor_off + p * 9 + a) * kout + c] = acc[j][i] + bv;
            }
        }
    }
}

extern "C" void kernel_launch(void* const* d_in, const int* in_sizes, int n_in,
                              void* d_out, int out_size, void* d_ws, size_t ws_size,
                              hipStream_t stream) {
    const float* feats[5];
    for (int i = 0; i < 5; i++) feats[i] = (const float*)d_in[i];
    const float* cls_conv_w = (const float*)d_in[5];
    const float* cls_conv_b = (const float*)d_in[6];
    const float* cls_out_w  = (const float*)d_in[7];
    const float* cls_out_b  = (const float*)d_in[8];
    const float* reg_conv_w = (const float*)d_in[9];
    const float* reg_conv_b = (const float*)d_in[10];
    const float* reg_out_w  = (const float*)d_in[11];
    const float* reg_out_b  = (const float*)d_in[12];

    // ping-pong activation buffers: 2 * 256 * 128 * 128 floats each (33.55 MB)
    float* buf0 = (float*)d_ws;
    float* buf1 = buf0 + (size_t)2 * 256 * 128 * 128;

    const int sizes[5]  = {128, 64, 32, 16, 8};
    const int shifts[5] = {7, 6, 5, 4, 3};
    const int ATOT = 196416;   // sum(H*W)*9 = 21824*9

    float* outs[2]        = { (float*)d_out, (float*)d_out + (size_t)2 * ATOT * 91 };
    const float* convw[2] = { cls_conv_w, reg_conv_w };
    const float* convb[2] = { cls_conv_b, reg_conv_b };
    const float* outw[2]  = { cls_out_w, reg_out_w };
    const float* outb[2]  = { cls_out_b, reg_out_b };
    const int OCf[2]   = { 9 * 91, 9 * 4 };
    const int kouts[2] = { 91, 4 };

    int anchor_off = 0;
    for (int s = 0; s < 5; s++) {
        const int H = sizes[s], W = sizes[s], M = H * W;
        for (int h = 0; h < 2; h++) {
            const float* src = feats[s];
            float* dst = buf0;
            for (int l = 0; l < 4; l++) {
                dim3 grid(M / TM, 256 / TN, 2);
                conv3x3_mid<<<grid, dim3(16, 16), 0, stream>>>(
                    src, convw[h] + (size_t)l * 256 * KTOT, convb[h] + l * 256,
                    dst, H, W, shifts[s]);
                src = dst;
                dst = (dst == buf0) ? buf1 : buf0;
            }
            dim3 gridf(M / TM, (OCf[h] + TN - 1) / TN, 2);
            conv3x3_final<<<gridf, dim3(16, 16), 0, stream>>>(
                src, outw[h], outb[h], outs[h],
                H, W, shifts[s], OCf[h], kouts[h], anchor_off, ATOT);
        }
        anchor_off += M * 9;
    }
}

// Round 2
// 2845.127 us; speedup vs baseline: 8.5064x; 8.5064x over previous
//
#include <hip/hip_runtime.h>
#include <hip/hip_bf16.h>

typedef __attribute__((ext_vector_type(8))) short   short8;
typedef __attribute__((ext_vector_type(4))) float   floatx4;
typedef __attribute__((ext_vector_type(4))) unsigned short ushort4v;

#define ICH 256

// ---------------- conversion kernels ----------------

// feats: [n][256][M] f32 -> [n][M][256] bf16 (LDS transpose)
__global__ __launch_bounds__(256)
void convert_feats(const float* __restrict__ in, __hip_bfloat16* __restrict__ out, int M) {
    __shared__ float t[64][65];
    const int p0 = blockIdx.x * 64, n = blockIdx.y;
    const int tid = threadIdx.x;
    const float* ib = in + (size_t)n * ICH * M;
    __hip_bfloat16* ob = out + (size_t)n * M * ICH;
    const int lo = tid & 63, hi = tid >> 6;
    for (int c0 = 0; c0 < ICH; c0 += 64) {
        #pragma unroll
        for (int r = 0; r < 16; ++r) {
            int ic = hi + 4 * r;
            t[ic][lo] = ib[(size_t)(c0 + ic) * M + p0 + lo];
        }
        __syncthreads();
        #pragma unroll
        for (int r = 0; r < 16; ++r) {
            int pp = hi + 4 * r;
            ob[(size_t)(p0 + pp) * ICH + c0 + lo] = __float2bfloat16(t[lo][pp]);
        }
        __syncthreads();
    }
}

// mid weights: [4][256][256][9] f32 -> [4][9][256][256] bf16
__global__ __launch_bounds__(256)
void convert_wmid(const float* __restrict__ in, __hip_bfloat16* __restrict__ out) {
    int idx = blockIdx.x * 256 + threadIdx.x;   // 4*9*256*256 total
    int ic = idx & 255, r = idx >> 8;
    int oc = r & 255, r2 = r >> 8;              // r2 = l*9+s
    int s = r2 % 9, l = r2 / 9;
    out[idx] = __float2bfloat16(in[(size_t)((l * 256 + oc) * 256 + ic) * 9 + s]);
}

// final weights: [OC][256][9] f32 -> [9][OCpad][256] bf16 (zero-padded)
__global__ __launch_bounds__(256)
void convert_wfin(const float* __restrict__ in, __hip_bfloat16* __restrict__ out,
                  int OC, int OCpad) {
    int idx = blockIdx.x * 256 + threadIdx.x;   // 9*OCpad*256 total
    int ic = idx & 255, r = idx >> 8;
    int oc = r % OCpad, s = r / OCpad;
    float v = 0.0f;
    if (oc < OC) v = in[(size_t)(oc * 256 + ic) * 9 + s];
    out[idx] = __float2bfloat16(v);
}

// ---------------- MFMA conv kernel ----------------
// actin : bf16 [n][M][256]   (ic contiguous)
// wsrc  : bf16 [9][OCL][256]
// mid   : actout bf16 [n][M][256], ReLU(conv+bias)
// final : fout fp32, out[(anchor_off + p*9 + a)*KOUT + c] = conv+bias, oc = a*KOUT+c
template<int BW, bool FINAL, int KOUT>
__global__ __launch_bounds__(256, 2)
void conv_mfma(const __hip_bfloat16* __restrict__ actin,
               const __hip_bfloat16* __restrict__ wsrc,
               const float* __restrict__ bias,
               __hip_bfloat16* __restrict__ actout,
               float* __restrict__ fout,
               int H, int W, int nbX, int OCL, int OC,
               int anchor_off, int atot)
{
    constexpr int BH   = 128 / BW;
    constexpr int BWP  = BW + 2;
    constexpr int BHP  = BH + 2;
    constexpr int HTOT = BWP * BHP;   // 180 for both configs

    __shared__ short lds_act[HTOT * 64];
    __shared__ short lds_w[128 * 64];

    const int M  = H * W;
    const int n  = blockIdx.z;
    const int by = blockIdx.x / nbX;
    const int bx = blockIdx.x - by * nbX;
    const int y0 = by * BH, x0 = bx * BW;
    const int oc0 = blockIdx.y * 128;
    const int tid  = threadIdx.x;
    const int lane = tid & 63, wv = tid >> 6;
    const int mw = wv >> 1, nw = wv & 1;
    const int ln = lane & 15, q = lane >> 4;
    const int sub = tid & 7, grp = tid >> 3;    // 0..7, 0..31

    const short* actg = (const short*)actin + (size_t)n * M * ICH;
    const short* wg   = (const short*)wsrc;

    int base_a[4], base_b[4];
    #pragma unroll
    for (int j = 0; j < 4; ++j)
        base_a[j] = (mw * 64 + 16 * j + ln) * 64 + q * 8;
    #pragma unroll
    for (int i = 0; i < 4; ++i) {
        int t  = nw * 64 + 16 * i + ln;
        int ty = t / BW, tx = t % BW;
        base_b[i] = ((ty + 1) * BWP + tx + 1) * 64 + q * 8;
    }

    floatx4 acc[4][4] = {};

    short8 wreg[4];
    auto loadw = [&](int s, int icb) {
        #pragma unroll
        for (int it = 0; it < 4; ++it) {
            int ocl = grp + 32 * it;
            wreg[it] = *(const short8*)(wg + ((size_t)(s * OCL + oc0 + ocl) * ICH
                                              + icb * 64 + sub * 8));
        }
    };

    loadw(0, 0);

    for (int icb = 0; icb < 4; ++icb) {
        // stage activation halo tile (180 px x 64 ic) for this channel block
        #pragma unroll
        for (int it = 0; it < 6; ++it) {
            int hp = grp + 32 * it;
            if (hp < HTOT) {
                int hy = hp / BWP, hx = hp - hy * BWP;
                int gy = y0 - 1 + hy, gx = x0 - 1 + hx;
                short8 v = {};
                if ((unsigned)gy < (unsigned)H && (unsigned)gx < (unsigned)W)
                    v = *(const short8*)(actg + ((size_t)(gy * W + gx) * ICH
                                                 + icb * 64 + sub * 8));
                *(short8*)(&lds_act[hp * 64 + sub * 8]) = v;
            }
        }
        #pragma unroll
        for (int s = 0; s < 9; ++s) {
            // write prefetched weight tile to LDS
            #pragma unroll
            for (int it = 0; it < 4; ++it)
                *(short8*)(&lds_w[(grp + 32 * it) * 64 + sub * 8]) = wreg[it];
            __syncthreads();
            // prefetch next weight tile (overlaps with MFMA below)
            if (s < 8)          loadw(s + 1, icb);
            else if (icb < 3)   loadw(0, icb + 1);

            const int dy = s / 3 - 1, dx = s % 3 - 1;
            const int soff = (dy * BWP + dx) * 64;
            #pragma unroll
            for (int kk = 0; kk < 2; ++kk) {
                short8 af[4], bf[4];
                #pragma unroll
                for (int j = 0; j < 4; ++j)
                    af[j] = *(const short8*)(&lds_w[base_a[j] + 32 * kk]);
                #pragma unroll
                for (int i = 0; i < 4; ++i)
                    bf[i] = *(const short8*)(&lds_act[base_b[i] + soff + 32 * kk]);
                #pragma unroll
                for (int j = 0; j < 4; ++j)
                    #pragma unroll
                    for (int i = 0; i < 4; ++i)
                        acc[j][i] = __builtin_amdgcn_mfma_f32_16x16x32_bf16(
                            af[j], bf[i], acc[j][i], 0, 0, 0);
            }
            __syncthreads();
        }
    }

    // ---------------- epilogue ----------------
    if constexpr (!FINAL) {
        __hip_bfloat16* ob = actout + (size_t)n * M * ICH;
        #pragma unroll
        for (int j = 0; j < 4; ++j) {
            int oc = oc0 + mw * 64 + 16 * j + q * 4;
            float bv[4];
            #pragma unroll
            for (int r = 0; r < 4; ++r) bv[r] = bias[oc + r];
            #pragma unroll
            for (int i = 0; i < 4; ++i) {
                int t  = nw * 64 + 16 * i + ln;
                int ty = t / BW, tx = t % BW;
                int gy = y0 + ty;
                if (gy < H) {
                    union { ushort4v v; __hip_bfloat16 h[4]; } u;
                    #pragma unroll
                    for (int r = 0; r < 4; ++r)
                        u.h[r] = __float2bfloat16(fmaxf(acc[j][i][r] + bv[r], 0.0f));
                    *(ushort4v*)(ob + (size_t)(gy * W + x0 + tx) * ICH + oc) = u.v;
                }
            }
        }
    } else {
        float* fb = fout + (size_t)n * atot * KOUT;
        #pragma unroll
        for (int j = 0; j < 4; ++j) {
            int ocb = oc0 + mw * 64 + 16 * j + q * 4;
            #pragma unroll
            for (int i = 0; i < 4; ++i) {
                int t  = nw * 64 + 16 * i + ln;
                int ty = t / BW, tx = t % BW;
                int gy = y0 + ty;
                if (gy < H) {
                    int p = gy * W + x0 + tx;
                    #pragma unroll
                    for (int r = 0; r < 4; ++r) {
                        int oc = ocb + r;
                        if (oc < OC) {
                            int a = oc / KOUT, c = oc - a * KOUT;
                            fb[(size_t)(anchor_off + p * 9 + a) * KOUT + c] =
                                acc[j][i][r] + bias[oc];
                        }
                    }
                }
            }
        }
    }
}

// ---------------- host ----------------

extern "C" void kernel_launch(void* const* d_in, const int* in_sizes, int n_in,
                              void* d_out, int out_size, void* d_ws, size_t ws_size,
                              hipStream_t stream) {
    const float* feats[5];
    for (int i = 0; i < 5; i++) feats[i] = (const float*)d_in[i];
    const float* cls_conv_w = (const float*)d_in[5];
    const float* cls_conv_b = (const float*)d_in[6];
    const float* cls_out_w  = (const float*)d_in[7];
    const float* cls_out_b  = (const float*)d_in[8];
    const float* reg_conv_w = (const float*)d_in[9];
    const float* reg_conv_b = (const float*)d_in[10];
    const float* reg_out_w  = (const float*)d_in[11];
    const float* reg_out_b  = (const float*)d_in[12];

    // workspace layout (64.5 MB total; round-1 verified >= 67 MB available)
    char* wp = (char*)d_ws;
    __hip_bfloat16* featC = (__hip_bfloat16*)wp; wp += (size_t)2 * 16384 * 256 * 2;
    __hip_bfloat16* actA  = (__hip_bfloat16*)wp; wp += (size_t)2 * 16384 * 256 * 2;
    __hip_bfloat16* actB  = (__hip_bfloat16*)wp; wp += (size_t)2 * 16384 * 256 * 2;
    __hip_bfloat16* wmid[2];
    wmid[0] = (__hip_bfloat16*)wp; wp += (size_t)4 * 9 * 256 * 256 * 2;
    wmid[1] = (__hip_bfloat16*)wp; wp += (size_t)4 * 9 * 256 * 256 * 2;
    __hip_bfloat16* wfc = (__hip_bfloat16*)wp; wp += (size_t)9 * 896 * 256 * 2;
    __hip_bfloat16* wfr = (__hip_bfloat16*)wp; wp += (size_t)9 * 128 * 256 * 2;

    // one-time weight conversions
    convert_wmid<<<4 * 9 * 256, 256, 0, stream>>>(cls_conv_w, wmid[0]);
    convert_wmid<<<4 * 9 * 256, 256, 0, stream>>>(reg_conv_w, wmid[1]);
    convert_wfin<<<9 * 896, 256, 0, stream>>>(cls_out_w, wfc, 819, 896);
    convert_wfin<<<9 * 128, 256, 0, stream>>>(reg_out_w, wfr, 36, 128);

    const int sizes[5] = {128, 64, 32, 16, 8};
    const int ATOT = 196416;   // sum(H*W)*9

    float* cls_out = (float*)d_out;
    float* reg_out = (float*)d_out + (size_t)2 * ATOT * 91;
    const float* convb[2] = { cls_conv_b, reg_conv_b };

    int aoff = 0;
    for (int sc = 0; sc < 5; ++sc) {
        const int Hs = sizes[sc], Ws = sizes[sc], M = Hs * Ws;
        const int BWv = (Ws >= 16) ? 16 : 8;
        const int BHv = 128 / BWv;
        const int nbX = (Ws + BWv - 1) / BWv;
        const int nbY = (Hs + BHv - 1) / BHv;
        dim3 gmid(nbX * nbY, 2, 2);

        convert_feats<<<dim3(M / 64, 2), 256, 0, stream>>>(feats[sc], featC, M);

        for (int h = 0; h < 2; ++h) {
            const __hip_bfloat16* src = featC;
            __hip_bfloat16* dst = actA;
            for (int l = 0; l < 4; ++l) {
                const __hip_bfloat16* wl = wmid[h] + (size_t)l * 9 * 256 * 256;
                const float* bl = convb[h] + l * 256;
                if (BWv == 16)
                    conv_mfma<16, false, 1><<<gmid, 256, 0, stream>>>(
                        src, wl, bl, dst, nullptr, Hs, Ws, nbX, 256, 256, 0, 0);
                else
                    conv_mfma<8, false, 1><<<gmid, 256, 0, stream>>>(
                        src, wl, bl, dst, nullptr, Hs, Ws, nbX, 256, 256, 0, 0);
                src = dst;
                dst = (dst == actA) ? actB : actA;
            }
            if (h == 0) {
                dim3 gf(nbX * nbY, 7, 2);   // 896/128
                if (BWv == 16)
                    conv_mfma<16, true, 91><<<gf, 256, 0, stream>>>(
                        src, wfc, cls_out_b, nullptr, cls_out, Hs, Ws, nbX, 896, 819, aoff, ATOT);
                else
                    conv_mfma<8, true, 91><<<gf, 256, 0, stream>>>(
                        src, wfc, cls_out_b, nullptr, cls_out, Hs, Ws, nbX, 896, 819, aoff, ATOT);
            } else {
                dim3 gf(nbX * nbY, 1, 2);   // 128/128
                if (BWv == 16)
                    conv_mfma<16, true, 4><<<gf, 256, 0, stream>>>(
                        src, wfr, reg_out_b, nullptr, reg_out, Hs, Ws, nbX, 128, 36, aoff, ATOT);
                else
                    conv_mfma<8, true, 4><<<gf, 256, 0, stream>>>(
                        src, wfr, reg_out_b, nullptr, reg_out, Hs, Ws, nbX, 128, 36, aoff, ATOT);
            }
        }
        aoff += M * 9;
    }
}